// Round 2
// 426.651 us; speedup vs baseline: 1.1190x; 1.1190x over previous
//
#include <hip/hip_runtime.h>

// Problem constants (match reference)
#define BGRAPH 64
#define NNODE  128
#define EMB    16
#define OUTF   64
#define EREAL  65536
#define TOTAL  (BGRAPH * NNODE * NNODE)   // 1048576 pairs

// Native clang vector type — required by __builtin_nontemporal_{load,store}
// (HIP's float4 is a class and is rejected by the builtin).
typedef float floatx4 __attribute__((ext_vector_type(4)));

// GEMM: 8192 blocks, 32 rows per block-iteration, 4 grid-stride iterations.
#define GEMM_BLOCKS 8192
#define ROWS_PER_BLOCK_ITER 32
#define GEMM_ITERS (TOTAL / (GEMM_BLOCKS * ROWS_PER_BLOCK_ITER))   // = 4

// Kernel 1: out_val[p][o] = sum_k gm_val[p][k] * W[o][k]
// 16 threads per row, each computes 4 contiguous outputs; W slice in registers.
// 2 rows per thread per iteration (2x ILP) and an explicit software prefetch
// of the NEXT iteration's 8 float4 loads issued BEFORE the current
// iteration's FMAs. Previously the wave sat at s_waitcnt vmcnt(0) for ~600
// cycles every iteration (VALUBusy 13.5%, 1.5 TB/s); now the load latency is
// hidden under 256 cycles of FMA work. Stores are non-temporal: out_val is
// written once, don't let 256 MiB of stores evict gm_val from L2/L3.
__global__ __launch_bounds__(256) void gemm_rows_kernel(
    const float* __restrict__ gm_val,
    const float* __restrict__ W,
    float* __restrict__ out_val)
{
    const int tid = threadIdx.x;
    const int oq  = tid & 15;     // output quad: outputs [4*oq, 4*oq+3]
    const int rg  = tid >> 4;     // row group 0..15

    // Load my 4 rows of W (contiguous 64 floats) into registers. W is 4 KB
    // total -> L2-resident broadcast across all blocks.
    float w[4][16];
    const floatx4* W4 = (const floatx4*)W + oq * 16;
    #pragma unroll
    for (int j = 0; j < 4; ++j) {
        #pragma unroll
        for (int q = 0; q < 4; ++q) {
            floatx4 t = W4[j * 4 + q];
            w[j][q * 4 + 0] = t.x;
            w[j][q * 4 + 1] = t.y;
            w[j][q * 4 + 2] = t.z;
            w[j][q * 4 + 3] = t.w;
        }
    }

    const int stride = GEMM_BLOCKS * ROWS_PER_BLOCK_ITER;   // 262144 rows
    int rA = blockIdx.x * ROWS_PER_BLOCK_ITER + rg;         // rows rA, rA+16
    int rB = rA + 16;

    // Pipeline prologue: load iteration 0's two rows.
    const floatx4* pA = (const floatx4*)(gm_val + (size_t)rA * EMB);
    const floatx4* pB = (const floatx4*)(gm_val + (size_t)rB * EMB);
    floatx4 c0 = pA[0], c1 = pA[1], c2 = pA[2], c3 = pA[3];
    floatx4 d0 = pB[0], d1 = pB[1], d2 = pB[2], d3 = pB[3];

    #pragma unroll
    for (int it = 0; it < GEMM_ITERS; ++it) {
        // Prefetch next iteration's rows BEFORE consuming current ones.
        floatx4 n0, n1, n2, n3, m0, m1, m2, m3;
        if (it + 1 < GEMM_ITERS) {
            const floatx4* qA = (const floatx4*)(gm_val + (size_t)(rA + stride) * EMB);
            const floatx4* qB = (const floatx4*)(gm_val + (size_t)(rB + stride) * EMB);
            n0 = qA[0]; n1 = qA[1]; n2 = qA[2]; n3 = qA[3];
            m0 = qB[0]; m1 = qB[1]; m2 = qB[2]; m3 = qB[3];
        }

        // Row A: 64 FMAs + one 16 B NT store.
        {
            float v[16] = {c0.x,c0.y,c0.z,c0.w, c1.x,c1.y,c1.z,c1.w,
                           c2.x,c2.y,c2.z,c2.w, c3.x,c3.y,c3.z,c3.w};
            float s0 = 0.f, s1 = 0.f, s2 = 0.f, s3 = 0.f;
            #pragma unroll
            for (int k = 0; k < EMB; ++k) {
                s0 += v[k] * w[0][k];
                s1 += v[k] * w[1][k];
                s2 += v[k] * w[2][k];
                s3 += v[k] * w[3][k];
            }
            floatx4 o = {s0, s1, s2, s3};
            __builtin_nontemporal_store(o, (floatx4*)(out_val + (size_t)rA * OUTF + oq * 4));
        }
        // Row B
        {
            float v[16] = {d0.x,d0.y,d0.z,d0.w, d1.x,d1.y,d1.z,d1.w,
                           d2.x,d2.y,d2.z,d2.w, d3.x,d3.y,d3.z,d3.w};
            float s0 = 0.f, s1 = 0.f, s2 = 0.f, s3 = 0.f;
            #pragma unroll
            for (int k = 0; k < EMB; ++k) {
                s0 += v[k] * w[0][k];
                s1 += v[k] * w[1][k];
                s2 += v[k] * w[2][k];
                s3 += v[k] * w[3][k];
            }
            floatx4 o = {s0, s1, s2, s3};
            __builtin_nontemporal_store(o, (floatx4*)(out_val + (size_t)rB * OUTF + oq * 4));
        }

        // Rotate pipeline registers (dead on last iteration -> DCE'd).
        c0 = n0; c1 = n1; c2 = n2; c3 = n3;
        d0 = m0; d1 = m1; d2 = m2; d3 = m3;
        rA += stride; rB += stride;
    }
}

// Kernel 2: atomic scatter-add of real-edge attrs + closed-form index output
// merged into one launch (idx writes overlap the atomic-bound scatter).
// Scatter: one thread per (edge, channel); a 64-lane wave covers one edge's
// 64 contiguous channels (one 256 B segment -> coalesced atomics).
#define SCATTER_BLOCKS ((EREAL * OUTF) / 256)   // 16384
#define IDX_BLOCKS (TOTAL / 256)                // 4096

__global__ __launch_bounds__(256) void scatter_idx_kernel(
    const int* __restrict__ edge_index,   // [2, EREAL] flat: src then dst
    const float* __restrict__ edge_attr,  // [EREAL, OUTF]
    float* __restrict__ out_val,
    float* __restrict__ out_idx)
{
    int bid = blockIdx.x;
    if (bid < SCATTER_BLOCKS) {
        int idx = bid * 256 + threadIdx.x;
        int e = idx >> 6;
        int o = idx & 63;
        int src = edge_index[e];
        int dst = edge_index[EREAL + e];
        int fid = src * NNODE + (dst & (NNODE - 1));   // src*128 + dst%128
        float a = __builtin_nontemporal_load(edge_attr + (size_t)e * OUTF + o);
        atomicAdd(out_val + (size_t)fid * OUTF + o, a);
    } else {
        int p = (bid - SCATTER_BLOCKS) * 256 + threadIdx.x;   // p in [0, TOTAL)
        int g   = p >> 14;          // / (N*N)
        int rem = p & 16383;        // % (N*N)
        out_idx[p]         = (float)(g * NNODE + (rem >> 7));   // src row
        out_idx[TOTAL + p] = (float)(g * NNODE + (rem & 127));  // dst row
    }
}

extern "C" void kernel_launch(void* const* d_in, const int* in_sizes, int n_in,
                              void* d_out, int out_size, void* d_ws, size_t ws_size,
                              hipStream_t stream)
{
    // inputs (setup_inputs order): batch, edge_index, edge_attr, gm_index, gm_val, W
    const int*   edge_index = (const int*)d_in[1];
    const float* edge_attr  = (const float*)d_in[2];
    const float* gm_val     = (const float*)d_in[4];
    const float* W          = (const float*)d_in[5];

    float* out      = (float*)d_out;
    float* out_idx  = out;                     // first 2*TOTAL elements
    float* out_val  = out + (size_t)2 * TOTAL; // then TOTAL*OUTF elements

    // 1) dense gm projection (overwrites poison), software-pipelined
    gemm_rows_kernel<<<GEMM_BLOCKS, 256, 0, stream>>>(gm_val, W, out_val);
    // 2) scatter-add real edges + index output (same stream serializes after 1)
    scatter_idx_kernel<<<SCATTER_BLOCKS + IDX_BLOCKS, 256, 0, stream>>>(
        edge_index, edge_attr, out_val, out_idx);
}